// Round 7
// baseline (864.298 us; speedup 1.0000x reference)
//
#include <hip/hip_runtime.h>
#include <float.h>

// VQ-VAE quantizer: z [16,64,64,64] f32 (NCHW), embedding [1024,64] f32.
// d_out (f32): [loss(1) | z_q_out(4194304) | one_hot(67108864) | indices(65536)]
// train_indices must match numpy's fp32 argmin BIT-EXACTLY (verified: absmax 0.0
// in round 3). Scoring math below is frozen — do not alter rounding semantics.
// This round: remove the 285 MB output memset; one-hot rows are written
// (zeros + single 1.0) by a fused combine+onehot kernel, one block per point.

#define K_CODES 1024
#define DIM 64
#define NPTS 65536            // 16*64*64 points
#define RANGES 8
#define CPR 128               // codes per range
#define ZQ_OFF 1
#define OH_OFF (1 + 4194304)
#define IDX_OFF (1 + 4194304 + 67108864)

// numpy pairwise_sum of x[c]*x[c], n=64: classic 8-accumulator pattern.
// contract(off): numpy squares into a rounded fp32 temp BEFORE summing — no fma.
__device__ __forceinline__ float np_sumsq64(const float* x) {
#pragma clang fp contract(off)
    float t[DIM];
#pragma unroll
    for (int c = 0; c < DIM; ++c) t[c] = x[c] * x[c];
    float r[8];
#pragma unroll
    for (int j = 0; j < 8; ++j) r[j] = t[j];
#pragma unroll
    for (int i = 8; i < DIM; i += 8)
#pragma unroll
        for (int j = 0; j < 8; ++j) r[j] += t[i + j];
    return ((r[0] + r[1]) + (r[2] + r[3])) + ((r[4] + r[5]) + (r[6] + r[7]));
}

__global__ __launch_bounds__(256) void bk_kernel(const float* __restrict__ emb,
                                                 float* __restrict__ bkf) {
    int k = blockIdx.x * 256 + threadIdx.x;
    if (k >= K_CODES) return;
    bkf[k] = np_sumsq64(emb + (size_t)k * DIM);
}

// Each block: 256 points x 128 codes (one k-range).
// d_k = fl( fl(A + B_k) - 2*fl(serial-fma dot) )  -- numpy/BLAS semantics. FROZEN.
__global__ __launch_bounds__(256) void argmin_partial(
    const float* __restrict__ z, const float* __restrict__ emb,
    const float* __restrict__ bkf,
    float* __restrict__ pscore, int* __restrict__ pidx) {
    int t = threadIdx.x;
    int ptblk = blockIdx.x & 255;
    int range = blockIdx.x >> 8;
    int kbase = range * CPR;

    int n = ptblk * 256 + t;
    int b = n >> 12, hw = n & 4095;
    const float* zb = z + ((size_t)b << 18) + hw;   // b*64*4096 + hw
    float zd[DIM];
#pragma unroll
    for (int c = 0; c < DIM; ++c) zd[c] = zb[(size_t)c << 12];

    float A = np_sumsq64(zd);

    float best = FLT_MAX;
    int bi = kbase;
#pragma unroll 2
    for (int k = 0; k < CPR; ++k) {
        const float4* e4 = (const float4*)(emb + (size_t)(kbase + k) * DIM);
        float m = 0.0f;
#pragma unroll
        for (int i = 0; i < 16; ++i) {
            float4 v = e4[i];   // wave-uniform address -> scalar loads
            m = __builtin_fmaf(zd[i * 4 + 0], v.x, m);
            m = __builtin_fmaf(zd[i * 4 + 1], v.y, m);
            m = __builtin_fmaf(zd[i * 4 + 2], v.z, m);
            m = __builtin_fmaf(zd[i * 4 + 3], v.w, m);
        }
        float d;
        {
#pragma clang fp contract(off)
            float t1 = A + bkf[kbase + k];
            d = t1 - 2.0f * m;
        }
        if (d < best) { best = d; bi = kbase + k; }   // strict <: first index wins
    }
    pscore[range * NPTS + n] = best;
    pidx[range * NPTS + n] = bi;
}

// One block per point: combine 8 range-partials (ascending -> first-index ties),
// then write the ENTIRE one-hot row (zeros + one 1.0) -- replaces the memset.
// Row base is 4-byte-aligned only (OH_OFF%4==1), so use coalesced dword stores:
// thread t writes cols t, t+256, t+512, t+768.
__global__ __launch_bounds__(256) void onehot_combine(
    const float* __restrict__ pscore, const int* __restrict__ pidx,
    int* __restrict__ fidx, float* __restrict__ out) {
    int n = blockIdx.x;
    float best = pscore[n];               // wave-uniform loads (scalar)
    int bi = pidx[n];
#pragma unroll
    for (int r = 1; r < RANGES; ++r) {
        float s = pscore[r * NPTS + n];
        int i2 = pidx[r * NPTS + n];
        if (s < best) { best = s; bi = i2; }   // ascending: first idx wins
    }
    int t = threadIdx.x;
    if (t == 0) {
        fidx[n] = bi;
        out[IDX_OFF + n] = (float)bi;
    }
    float* row = out + OH_OFF + (size_t)n * K_CODES;
#pragma unroll
    for (int j = 0; j < 4; ++j) {
        int col = t + j * 256;
        row[col] = (col == bi) ? 1.0f : 0.0f;
    }
}

__global__ __launch_bounds__(256) void zq_loss_kernel(
    const float* __restrict__ z, const float* __restrict__ emb,
    const int* __restrict__ fidx, float* __restrict__ out) {
    int o = blockIdx.x * 256 + threadIdx.x;    // 4194304 elements, NCHW linear
    int hw = o & 4095;
    int c = (o >> 12) & 63;
    int b = o >> 18;
    int n = (b << 12) | hw;
    int idx = fidx[n];
    float zq = emb[(size_t)idx * DIM + c];
    float zp = z[o];
    out[ZQ_OFF + o] = zp + (zq - zp);          // straight-through (== z_q numerically)
    float d = zq - zp;
    float v = d * d;
#pragma unroll
    for (int off = 32; off; off >>= 1) v += __shfl_down(v, off, 64);
    __shared__ float wsum[4];
    if ((threadIdx.x & 63) == 0) wsum[threadIdx.x >> 6] = v;
    __syncthreads();
    if (threadIdx.x == 0) {
        float s = (wsum[0] + wsum[1]) + (wsum[2] + wsum[3]);
        // loss = (1 + beta) * mean((z_q - z)^2), beta = 0.25, N = 4194304
        atomicAdd(out, s * (1.25f / 4194304.0f));
    }
}

extern "C" void kernel_launch(void* const* d_in, const int* in_sizes, int n_in,
                              void* d_out, int out_size, void* d_ws, size_t ws_size,
                              hipStream_t stream) {
    const float* z = (const float*)d_in[0];
    const float* emb = (const float*)d_in[1];
    float* out = (float*)d_out;
    char* ws = (char*)d_ws;
    float* bkf = (float*)ws;                                     // 4 KB
    float* pscore = (float*)(ws + 8192);                         // 2 MB
    int* pidx = (int*)(ws + 8192 + (size_t)RANGES * NPTS * 4);   // 2 MB
    int* fidx = (int*)(ws + 8192 + (size_t)RANGES * NPTS * 8);   // 256 KB

    hipMemsetAsync(d_out, 0, 4, stream);   // loss accumulator only
    hipLaunchKernelGGL(bk_kernel, dim3(4), dim3(256), 0, stream, emb, bkf);
    hipLaunchKernelGGL(argmin_partial, dim3(256 * RANGES), dim3(256), 0, stream,
                       z, emb, bkf, pscore, pidx);
    hipLaunchKernelGGL(onehot_combine, dim3(NPTS), dim3(256), 0, stream,
                       pscore, pidx, fidx, out);
    hipLaunchKernelGGL(zq_loss_kernel, dim3(4194304 / 256), dim3(256), 0, stream,
                       z, emb, fidx, out);
}

// Round 9
// 572.465 us; speedup vs baseline: 1.5098x; 1.5098x over previous
//
#include <hip/hip_runtime.h>
#include <float.h>

// VQ-VAE quantizer: z [16,64,64,64] f32 (NCHW), embedding [1024,64] f32.
// d_out (f32): [loss(1) | z_q_out(4194304) | one_hot(67108864) | indices(65536)]
// train_indices match numpy fp32 argmin BIT-EXACTLY (absmax 0.0, rounds 3/7).
// argmin_partial is FROZEN. This round: (a) one-hot via vectorized bulk fill
// (268 MB only) + tiny scatter (r7's fused row-writer was 126 us SLOWER than
// memset+scatter); (b) zq_loss de-serialized: 1024 blocks, float4 stores,
// one atomicAdd per block instead of 16384 same-address atomics.

#define K_CODES 1024
#define DIM 64
#define NPTS 65536            // 16*64*64 points
#define RANGES 8
#define CPR 128               // codes per range
#define ZQ_OFF 1
#define OH_OFF (1 + 4194304)
#define IDX_OFF (1 + 4194304 + 67108864)
#define ZQ_N 4194304

// numpy pairwise_sum of x[c]*x[c], n=64: classic 8-accumulator pattern.
// contract(off): numpy squares into a rounded fp32 temp BEFORE summing — no fma.
__device__ __forceinline__ float np_sumsq64(const float* x) {
#pragma clang fp contract(off)
    float t[DIM];
#pragma unroll
    for (int c = 0; c < DIM; ++c) t[c] = x[c] * x[c];
    float r[8];
#pragma unroll
    for (int j = 0; j < 8; ++j) r[j] = t[j];
#pragma unroll
    for (int i = 8; i < DIM; i += 8)
#pragma unroll
        for (int j = 0; j < 8; ++j) r[j] += t[i + j];
    return ((r[0] + r[1]) + (r[2] + r[3])) + ((r[4] + r[5]) + (r[6] + r[7]));
}

__global__ __launch_bounds__(256) void bk_kernel(const float* __restrict__ emb,
                                                 float* __restrict__ bkf) {
    int k = blockIdx.x * 256 + threadIdx.x;
    if (k >= K_CODES) return;
    bkf[k] = np_sumsq64(emb + (size_t)k * DIM);
}

// FROZEN bit-exact scoring. Each block: 256 points x 128 codes (one k-range).
__global__ __launch_bounds__(256) void argmin_partial(
    const float* __restrict__ z, const float* __restrict__ emb,
    const float* __restrict__ bkf,
    float* __restrict__ pscore, int* __restrict__ pidx) {
    int t = threadIdx.x;
    int ptblk = blockIdx.x & 255;
    int range = blockIdx.x >> 8;
    int kbase = range * CPR;

    int n = ptblk * 256 + t;
    int b = n >> 12, hw = n & 4095;
    const float* zb = z + ((size_t)b << 18) + hw;   // b*64*4096 + hw
    float zd[DIM];
#pragma unroll
    for (int c = 0; c < DIM; ++c) zd[c] = zb[(size_t)c << 12];

    float A = np_sumsq64(zd);

    float best = FLT_MAX;
    int bi = kbase;
#pragma unroll 2
    for (int k = 0; k < CPR; ++k) {
        const float4* e4 = (const float4*)(emb + (size_t)(kbase + k) * DIM);
        float m = 0.0f;
#pragma unroll
        for (int i = 0; i < 16; ++i) {
            float4 v = e4[i];
            m = __builtin_fmaf(zd[i * 4 + 0], v.x, m);
            m = __builtin_fmaf(zd[i * 4 + 1], v.y, m);
            m = __builtin_fmaf(zd[i * 4 + 2], v.z, m);
            m = __builtin_fmaf(zd[i * 4 + 3], v.w, m);
        }
        float d;
        {
#pragma clang fp contract(off)
            float t1 = A + bkf[kbase + k];
            d = t1 - 2.0f * m;
        }
        if (d < best) { best = d; bi = kbase + k; }   // strict <: first index wins
    }
    pscore[range * NPTS + n] = best;
    pidx[range * NPTS + n] = bi;
}

// Zero-fill ONLY the one-hot region (268 MB) with aligned float4 stores.
// Region dword range [OH_OFF, OH_OFF+67108864); OH_OFF%4==1, so quads start
// at OH_OFF+3; head 3 dwords + tail 1 dword handled by block 0 / thread 0.
#define OH_QUADS 16777215     // (67108864 - 3 - 1) / 4
__global__ __launch_bounds__(256) void fill_oh(float* __restrict__ out) {
    const float4 z4 = make_float4(0.f, 0.f, 0.f, 0.f);
    float4* qbase = (float4*)(out + OH_OFF + 3);
    int stride = gridDim.x * 256;
    for (int q = blockIdx.x * 256 + threadIdx.x; q < OH_QUADS; q += stride)
        qbase[q] = z4;
    if (blockIdx.x == 0 && threadIdx.x == 0) {
        out[OH_OFF] = 0.f; out[OH_OFF + 1] = 0.f; out[OH_OFF + 2] = 0.f;
        out[OH_OFF + 67108863] = 0.f;
    }
}

// Combine 8 range-partials per point (ascending -> first-index ties),
// write fidx, float idx, and scatter the single 1.0 into the zeroed one-hot.
__global__ __launch_bounds__(256) void combine_kernel(
    const float* __restrict__ pscore, const int* __restrict__ pidx,
    int* __restrict__ fidx, float* __restrict__ out) {
    int n = blockIdx.x * 256 + threadIdx.x;
    float best = pscore[n];
    int bi = pidx[n];
#pragma unroll
    for (int r = 1; r < RANGES; ++r) {
        float s = pscore[r * NPTS + n];
        if (s < best) { best = s; bi = pidx[r * NPTS + n]; }  // ascending: first idx wins
    }
    fidx[n] = bi;
    out[IDX_OFF + n] = (float)bi;
    out[OH_OFF + (size_t)n * K_CODES + bi] = 1.0f;
}

// Grid-stride over aligned quads of the z_q output region. Out dword offset
// ZQ_OFF+o with o=3+4q is 16B-aligned. Scalars o=0,1,2,4194303 done by
// block 0/thread 0 (their squares included in its partial sum).
#define ZQ_QUADS 1048575      // (4194304 - 3 - 1) / 4
__global__ __launch_bounds__(256) void zq_loss_kernel(
    const float* __restrict__ z, const float* __restrict__ emb,
    const int* __restrict__ fidx, float* __restrict__ out) {
    int tid = blockIdx.x * 256 + threadIdx.x;
    int stride = gridDim.x * 256;
    float acc = 0.0f;
    for (int q = tid; q < ZQ_QUADS; q += stride) {
        int o = 3 + 4 * q;
        float4 r;
        float* rp = (float*)&r;
#pragma unroll
        for (int j = 0; j < 4; ++j) {
            int oj = o + j;
            int hw = oj & 4095;
            int c = (oj >> 12) & 63;
            int b = oj >> 18;
            int n = (b << 12) | hw;
            float zq = emb[(size_t)fidx[n] * DIM + c];
            float zp = z[oj];
            rp[j] = zp + (zq - zp);
            float d = zq - zp;
            acc = __builtin_fmaf(d, d, acc);
        }
        *(float4*)(out + ZQ_OFF + o) = r;
    }
    if (tid == 0) {
        int extras[4] = {0, 1, 2, 4194303};
#pragma unroll
        for (int e = 0; e < 4; ++e) {
            int oj = extras[e];
            int hw = oj & 4095;
            int c = (oj >> 12) & 63;
            int b = oj >> 18;
            int n = (b << 12) | hw;
            float zq = emb[(size_t)fidx[n] * DIM + c];
            float zp = z[oj];
            out[ZQ_OFF + oj] = zp + (zq - zp);
            float d = zq - zp;
            acc = __builtin_fmaf(d, d, acc);
        }
    }
#pragma unroll
    for (int off = 32; off; off >>= 1) acc += __shfl_down(acc, off, 64);
    __shared__ float wsum[4];
    if ((threadIdx.x & 63) == 0) wsum[threadIdx.x >> 6] = acc;
    __syncthreads();
    if (threadIdx.x == 0) {
        float s = (wsum[0] + wsum[1]) + (wsum[2] + wsum[3]);
        // loss = (1 + beta) * mean((z_q - z)^2), beta = 0.25, N = 4194304
        atomicAdd(out, s * (1.25f / 4194304.0f));   // 1024 atomics total
    }
}

extern "C" void kernel_launch(void* const* d_in, const int* in_sizes, int n_in,
                              void* d_out, int out_size, void* d_ws, size_t ws_size,
                              hipStream_t stream) {
    const float* z = (const float*)d_in[0];
    const float* emb = (const float*)d_in[1];
    float* out = (float*)d_out;
    char* ws = (char*)d_ws;
    float* bkf = (float*)ws;                                     // 4 KB
    float* pscore = (float*)(ws + 8192);                         // 2 MB
    int* pidx = (int*)(ws + 8192 + (size_t)RANGES * NPTS * 4);   // 2 MB
    int* fidx = (int*)(ws + 8192 + (size_t)RANGES * NPTS * 8);   // 256 KB

    hipMemsetAsync(d_out, 0, 4, stream);   // loss accumulator
    hipLaunchKernelGGL(fill_oh, dim3(2048), dim3(256), 0, stream, out);
    hipLaunchKernelGGL(bk_kernel, dim3(4), dim3(256), 0, stream, emb, bkf);
    hipLaunchKernelGGL(argmin_partial, dim3(256 * RANGES), dim3(256), 0, stream,
                       z, emb, bkf, pscore, pidx);
    hipLaunchKernelGGL(combine_kernel, dim3(NPTS / 256), dim3(256), 0, stream,
                       pscore, pidx, fidx, out);
    hipLaunchKernelGGL(zq_loss_kernel, dim3(1024), dim3(256), 0, stream,
                       z, emb, fidx, out);
}